// Round 4
// baseline (1158.156 us; speedup 1.0000x reference)
//
#include <hip/hip_runtime.h>
#include <hip/hip_bf16.h>

// Problem constants (fixed by setup_inputs)
constexpr int NDA = 10000;   // target graph nodes
constexpr int NQ  = 64;      // query graph nodes
constexpr int CND = 1024;    // candidate set size
constexpr int DIN = 128;     // input feature dim
constexpr int D   = 256;     // hidden dim
constexpr int CAP = 96;      // max nnz per adjacency row (Poisson(20); P(>96) ~ 0)

#define LRELU(x) ((x) >= 0.f ? (x) : 0.01f * (x))

struct alignas(8) bf4 { __hip_bfloat16 a, b, c, d; };

__device__ __forceinline__ float wave_red64(float v) {
#pragma unroll
    for (int o = 32; o; o >>= 1) v += __shfl_down(v, o);
    return v;
}

// ---------------------------------------------------------------------------
// CSR build: one block per row, scan 10000 floats, record nonzero columns.
__global__ __launch_bounds__(256) void build_csr(const float* __restrict__ adj,
                                                 int* __restrict__ cols,
                                                 int* __restrict__ rowcnt) {
    int row = blockIdx.x;
    __shared__ int scnt;
    if (threadIdx.x == 0) scnt = 0;
    __syncthreads();
    const float4* rp = (const float4*)(adj + (size_t)row * NDA);
    for (int i = threadIdx.x; i < NDA / 4; i += 256) {
        float4 v = rp[i];
        if (v.x != 0.f) { int s = atomicAdd(&scnt, 1); if (s < CAP) cols[row * CAP + s] = 4 * i; }
        if (v.y != 0.f) { int s = atomicAdd(&scnt, 1); if (s < CAP) cols[row * CAP + s] = 4 * i + 1; }
        if (v.z != 0.f) { int s = atomicAdd(&scnt, 1); if (s < CAP) cols[row * CAP + s] = 4 * i + 2; }
        if (v.w != 0.f) { int s = atomicAdd(&scnt, 1); if (s < CAP) cols[row * CAP + s] = 4 * i + 3; }
    }
    __syncthreads();
    if (threadIdx.x == 0) rowcnt[row] = min(scnt, CAP);
}

// ---------------------------------------------------------------------------
// SpMM via CSR over fp32 input, width W: out[row,:] = sum_{j in N(row)} X[j,:]
template <int W>
__global__ void spmm_f32(const int* __restrict__ cols,
                         const int* __restrict__ rowcnt,
                         const float* __restrict__ X,
                         float* __restrict__ out) {
    int row = blockIdx.x;
    int d = threadIdx.x;
    int cnt = rowcnt[row];
    __shared__ int sc[CAP];
    if (d < CAP && d < cnt) sc[d] = cols[row * CAP + d];
    __syncthreads();
    float a0 = 0.f, a1 = 0.f, a2 = 0.f, a3 = 0.f;
    int k = 0;
    for (; k + 4 <= cnt; k += 4) {
        a0 += X[(size_t)sc[k + 0] * W + d];
        a1 += X[(size_t)sc[k + 1] * W + d];
        a2 += X[(size_t)sc[k + 2] * W + d];
        a3 += X[(size_t)sc[k + 3] * W + d];
    }
    for (; k < cnt; k++) a0 += X[(size_t)sc[k] * W + d];
    out[(size_t)row * W + d] = (a0 + a1) + (a2 + a3);
}

// SpMM over bf16 input (lrelu pre-applied by producer), width 256.
__global__ void spmm_bf16(const int* __restrict__ cols,
                          const int* __restrict__ rowcnt,
                          const __hip_bfloat16* __restrict__ X,
                          float* __restrict__ out) {
    int row = blockIdx.x;
    int d = threadIdx.x;
    int cnt = rowcnt[row];
    __shared__ int sc[CAP];
    if (d < CAP && d < cnt) sc[d] = cols[row * CAP + d];
    __syncthreads();
    float a0 = 0.f, a1 = 0.f, a2 = 0.f, a3 = 0.f;
    int k = 0;
    for (; k + 4 <= cnt; k += 4) {
        a0 += __bfloat162float(X[(size_t)sc[k + 0] * D + d]);
        a1 += __bfloat162float(X[(size_t)sc[k + 1] * D + d]);
        a2 += __bfloat162float(X[(size_t)sc[k + 2] * D + d]);
        a3 += __bfloat162float(X[(size_t)sc[k + 3] * D + d]);
    }
    for (; k < cnt; k++) a0 += __bfloat162float(X[(size_t)sc[k] * D + d]);
    out[(size_t)row * D + d] = (a0 + a1) + (a2 + a3);
}

// ---------------------------------------------------------------------------
// fp32 tiled GEMM: C[M,N] = A[M,K] @ B[K,N]; 64x64 tile, 4x4/thread.
// RELU_C: lrelu on C. DUAL: also store lrelu(C) fp32 to C2.
// BF16OUT: also store lrelu(C) as bf16 to bfout. rowsq: atomicAdd per-row sum
// of squares of C (post-RELU_C) — fused candidate-norm computation.
template <bool RELU_C, bool DUAL, bool BF16OUT>
__global__ __launch_bounds__(256) void gemm64(const float* __restrict__ A,
                                              const float* __restrict__ B,
                                              float* __restrict__ C,
                                              float* __restrict__ C2,
                                              __hip_bfloat16* __restrict__ bfout,
                                              float* __restrict__ rowsq,
                                              int M, int N, int K) {
    __shared__ float As[16][68];
    __shared__ float Bs[16][68];
    const int bm = blockIdx.x * 64;
    const int bn = blockIdx.y * 64;
    const int tid = threadIdx.x;
    const int tx = tid & 15, ty = tid >> 4;
    float acc[4][4] = {};
    for (int k0 = 0; k0 < K; k0 += 16) {
        {
            int m = tid >> 2;
            int k4 = (tid & 3) * 4;
            float4 v = make_float4(0.f, 0.f, 0.f, 0.f);
            if (bm + m < M) v = *(const float4*)(A + (size_t)(bm + m) * K + k0 + k4);
            As[k4 + 0][m] = v.x; As[k4 + 1][m] = v.y; As[k4 + 2][m] = v.z; As[k4 + 3][m] = v.w;
        }
        {
            int kk = tid >> 4;
            int n4 = (tid & 15) * 4;
            float4 v = *(const float4*)(B + (size_t)(k0 + kk) * N + bn + n4);
            Bs[kk][n4 + 0] = v.x; Bs[kk][n4 + 1] = v.y; Bs[kk][n4 + 2] = v.z; Bs[kk][n4 + 3] = v.w;
        }
        __syncthreads();
#pragma unroll
        for (int kk = 0; kk < 16; kk++) {
            float av[4], bv[4];
#pragma unroll
            for (int i = 0; i < 4; i++) av[i] = As[kk][ty * 4 + i];
#pragma unroll
            for (int j = 0; j < 4; j++) bv[j] = Bs[kk][tx * 4 + j];
#pragma unroll
            for (int i = 0; i < 4; i++)
#pragma unroll
                for (int j = 0; j < 4; j++) acc[i][j] += av[i] * bv[j];
        }
        __syncthreads();
    }
#pragma unroll
    for (int i = 0; i < 4; i++) {
        int r = bm + ty * 4 + i;
        if (r < M) {
            float4 v;
            v.x = acc[i][0]; v.y = acc[i][1]; v.z = acc[i][2]; v.w = acc[i][3];
            if (RELU_C) { v.x = LRELU(v.x); v.y = LRELU(v.y); v.z = LRELU(v.z); v.w = LRELU(v.w); }
            *(float4*)(C + (size_t)r * N + bn + tx * 4) = v;
            if (rowsq) {
                float rp = v.x * v.x + v.y * v.y + v.z * v.z + v.w * v.w;
                atomicAdd(&rowsq[r], rp);
            }
            if (DUAL) {
                float4 u;
                u.x = LRELU(v.x); u.y = LRELU(v.y); u.z = LRELU(v.z); u.w = LRELU(v.w);
                *(float4*)(C2 + (size_t)r * N + bn + tx * 4) = u;
            }
            if (BF16OUT) {
                bf4 t;
                t.a = __float2bfloat16(LRELU(v.x));
                t.b = __float2bfloat16(LRELU(v.y));
                t.c = __float2bfloat16(LRELU(v.z));
                t.d = __float2bfloat16(LRELU(v.w));
                *(bf4*)(bfout + (size_t)r * N + bn + tx * 4) = t;
            }
        }
    }
}

// ---------------------------------------------------------------------------
// Fused query path: Xq = Fq @ Wq, q_out = lrelu(Qadj @ Xq), accumulate per-row
// sum-of-squares of q_out into rnqsq[64] (global atomics; pre-zeroed buffer).
__global__ __launch_bounds__(256) void qpath_kernel(const float* __restrict__ Fq,
                                                    const float* __restrict__ Wq,
                                                    const float* __restrict__ Qadj,
                                                    float* __restrict__ q_out,
                                                    float* __restrict__ rnqsq,
                                                    int K) {
    __shared__ float As[16][68];
    __shared__ float Bs[16][68];
    __shared__ float Xs[64][68];
    __shared__ float Qs[64][68];
    __shared__ float sq[64];
    const int bn = blockIdx.x * 64;
    const int tid = threadIdx.x;
    const int tx = tid & 15, ty = tid >> 4;
    float acc[4][4] = {};
    for (int k0 = 0; k0 < K; k0 += 16) {
        {
            int m = tid >> 2;
            int k4 = (tid & 3) * 4;
            float4 v = *(const float4*)(Fq + (size_t)m * K + k0 + k4);
            As[k4 + 0][m] = v.x; As[k4 + 1][m] = v.y; As[k4 + 2][m] = v.z; As[k4 + 3][m] = v.w;
        }
        {
            int kk = tid >> 4;
            int n4 = (tid & 15) * 4;
            float4 v = *(const float4*)(Wq + (size_t)(k0 + kk) * D + bn + n4);
            Bs[kk][n4 + 0] = v.x; Bs[kk][n4 + 1] = v.y; Bs[kk][n4 + 2] = v.z; Bs[kk][n4 + 3] = v.w;
        }
        __syncthreads();
#pragma unroll
        for (int kk = 0; kk < 16; kk++) {
            float av[4], bv[4];
#pragma unroll
            for (int i = 0; i < 4; i++) av[i] = As[kk][ty * 4 + i];
#pragma unroll
            for (int j = 0; j < 4; j++) bv[j] = Bs[kk][tx * 4 + j];
#pragma unroll
            for (int i = 0; i < 4; i++)
#pragma unroll
                for (int j = 0; j < 4; j++) acc[i][j] += av[i] * bv[j];
        }
        __syncthreads();
    }
#pragma unroll
    for (int i = 0; i < 4; i++)
#pragma unroll
        for (int j = 0; j < 4; j++) Xs[ty * 4 + i][tx * 4 + j] = acc[i][j];
    for (int l = tid; l < NQ * NQ; l += 256) Qs[l >> 6][l & 63] = Qadj[l];
    if (tid < 64) sq[tid] = 0.f;
    __syncthreads();
    float a2[4][4] = {};
#pragma unroll 4
    for (int kk = 0; kk < NQ; kk++) {
        float av[4], bv[4];
#pragma unroll
        for (int i = 0; i < 4; i++) av[i] = Qs[ty * 4 + i][kk];
#pragma unroll
        for (int j = 0; j < 4; j++) bv[j] = Xs[kk][tx * 4 + j];
#pragma unroll
        for (int i = 0; i < 4; i++)
#pragma unroll
            for (int j = 0; j < 4; j++) a2[i][j] += av[i] * bv[j];
    }
#pragma unroll
    for (int i = 0; i < 4; i++) {
        float rp = 0.f;
#pragma unroll
        for (int j = 0; j < 4; j++) {
            float v = LRELU(a2[i][j]);
            q_out[(ty * 4 + i) * D + bn + tx * 4 + j] = v;
            rp += v * v;
        }
        atomicAdd(&sq[ty * 4 + i], rp);
    }
    __syncthreads();
    if (tid < 64) atomicAdd(&rnqsq[tid], sq[tid]);
}

// ---------------------------------------------------------------------------
// M[k,d] += sum over this block's candidate chunk of pn_c[k] * p_c[d],
// pn_c = p_c / max(|p_c|,1e-12) with |p_c| from fused rowsq.
constexpr int CCH = 128;
__global__ __launch_bounds__(256) void candM_split(const float* __restrict__ da,
                                                   const int* __restrict__ cand,
                                                   const float* __restrict__ rowsq,
                                                   float* __restrict__ M) {
    __shared__ float SA[8][64], SB[8][64];
    const int ti = blockIdx.x, tj = blockIdx.y;
    const int cb = blockIdx.z * CCH;
    const int tid = threadIdx.x;
    const int tx = tid & 15, ty = tid >> 4;
    float acc[4][4] = {};
    for (int c0 = 0; c0 < CCH; c0 += 8) {
        for (int l = tid; l < 512; l += 256) {
            int rr = l >> 6, c = l & 63;
            int cr = cand[cb + c0 + rr];
            float s = 1.f / fmaxf(sqrtf(rowsq[cr]), 1e-12f);
            SA[rr][c] = da[(size_t)cr * D + ti * 64 + c] * s;
            SB[rr][c] = da[(size_t)cr * D + tj * 64 + c];
        }
        __syncthreads();
#pragma unroll
        for (int rr = 0; rr < 8; rr++) {
            float av[4], bv[4];
#pragma unroll
            for (int i = 0; i < 4; i++) av[i] = SA[rr][ty * 4 + i];
#pragma unroll
            for (int j = 0; j < 4; j++) bv[j] = SB[rr][tx * 4 + j];
#pragma unroll
            for (int i = 0; i < 4; i++)
#pragma unroll
                for (int j = 0; j < 4; j++) acc[i][j] += av[i] * bv[j];
        }
        __syncthreads();
    }
#pragma unroll
    for (int i = 0; i < 4; i++)
#pragma unroll
        for (int j = 0; j < 4; j++)
            atomicAdd(&M[(ti * 64 + ty * 4 + i) * D + tj * 64 + tx * 4 + j], acc[i][j]);
}

// ---------------------------------------------------------------------------
// Fused h + att_q + emb: h = (diag(1/|q_r|) q) @ M; each block owns a 64-col
// slice, so col-norms of h, att_q = lrelu(q + h/colnorm), and emb (col means)
// are all block-local. Consume-zeros M for the next layer.
template <bool EMB>
__global__ __launch_bounds__(256) void hq_attq_kernel(const float* __restrict__ q,
                                                      const float* __restrict__ rnqsq,
                                                      float* __restrict__ M,
                                                      float* __restrict__ attq,
                                                      float* __restrict__ emb) {
    __shared__ float As[16][68];
    __shared__ float Bs[16][68];
    __shared__ float cred[16][64];
    __shared__ float sinv[64];
    const int bn = blockIdx.x * 64;
    const int tid = threadIdx.x;
    const int tx = tid & 15, ty = tid >> 4;
    const int am = tid >> 2;                 // A-staging row (fixed across k0)
    const float ascale = 1.f / fmaxf(sqrtf(rnqsq[am]), 1e-12f);
    float acc[4][4] = {};
    const float4 z4 = make_float4(0.f, 0.f, 0.f, 0.f);
    for (int k0 = 0; k0 < D; k0 += 16) {
        {
            int k4 = (tid & 3) * 4;
            float4 v = *(const float4*)(q + (size_t)am * D + k0 + k4);
            As[k4 + 0][am] = v.x * ascale; As[k4 + 1][am] = v.y * ascale;
            As[k4 + 2][am] = v.z * ascale; As[k4 + 3][am] = v.w * ascale;
        }
        {
            int kk = tid >> 4;
            int n4 = (tid & 15) * 4;
            float4 v = *(const float4*)(M + (size_t)(k0 + kk) * D + bn + n4);
            *(float4*)(M + (size_t)(k0 + kk) * D + bn + n4) = z4;   // consume-and-zero
            Bs[kk][n4 + 0] = v.x; Bs[kk][n4 + 1] = v.y; Bs[kk][n4 + 2] = v.z; Bs[kk][n4 + 3] = v.w;
        }
        __syncthreads();
#pragma unroll
        for (int kk = 0; kk < 16; kk++) {
            float av[4], bv[4];
#pragma unroll
            for (int i = 0; i < 4; i++) av[i] = As[kk][ty * 4 + i];
#pragma unroll
            for (int j = 0; j < 4; j++) bv[j] = Bs[kk][tx * 4 + j];
#pragma unroll
            for (int i = 0; i < 4; i++)
#pragma unroll
                for (int j = 0; j < 4; j++) acc[i][j] += av[i] * bv[j];
        }
        __syncthreads();
    }
    // col norms of h: sum over the 64 q-rows (ty×i) for each of this thread's cols
#pragma unroll
    for (int j = 0; j < 4; j++) {
        float p = 0.f;
#pragma unroll
        for (int i = 0; i < 4; i++) p += acc[i][j] * acc[i][j];
        cred[ty][tx * 4 + j] = p;
    }
    __syncthreads();
    if (tid < 64) {
        float s = 0.f;
#pragma unroll
        for (int t = 0; t < 16; t++) s += cred[t][tid];
        sinv[tid] = 1.f / fmaxf(sqrtf(s), 1e-12f);
    }
    __syncthreads();
    float esum[4] = {};
#pragma unroll
    for (int i = 0; i < 4; i++) {
        int r = ty * 4 + i;
        float4 q4 = *(const float4*)(q + (size_t)r * D + bn + tx * 4);
        float4 v;
        v.x = LRELU(q4.x + acc[i][0] * sinv[tx * 4 + 0]);
        v.y = LRELU(q4.y + acc[i][1] * sinv[tx * 4 + 1]);
        v.z = LRELU(q4.z + acc[i][2] * sinv[tx * 4 + 2]);
        v.w = LRELU(q4.w + acc[i][3] * sinv[tx * 4 + 3]);
        *(float4*)(attq + (size_t)r * D + bn + tx * 4) = v;
        if (EMB) { esum[0] += v.x; esum[1] += v.y; esum[2] += v.z; esum[3] += v.w; }
    }
    if (EMB) {
        __syncthreads();
#pragma unroll
        for (int j = 0; j < 4; j++) cred[ty][tx * 4 + j] = esum[j];
        __syncthreads();
        if (tid < 64) {
            float s = 0.f;
#pragma unroll
            for (int t = 0; t < 16; t++) s += cred[t][tid];
            emb[bn + tid] = s * (1.f / (float)NQ);
        }
    }
}

// ---------------------------------------------------------------------------
// end[i] = (a_i . emb)/max(|a_i|*|emb|,1e-8); m[i] = end>thr; cnt += m.
// |emb| computed in-block (emb is only 256 floats).
__global__ __launch_bounds__(256) void end_kernel(const float* __restrict__ A,
                                                  const float* __restrict__ emb,
                                                  const float* __restrict__ thr_p,
                                                  float* __restrict__ endv,
                                                  float* __restrict__ m,
                                                  float* __restrict__ cnt) {
    __shared__ float se[D];
    __shared__ float red[4];
    __shared__ float scnt, sembn;
    int d = threadIdx.x;
    se[d] = emb[d];
    if (d == 0) scnt = 0.f;
    __syncthreads();
    int w = d >> 6, lane = d & 63;
    {
        float p = wave_red64(se[d] * se[d]);
        if (lane == 0) red[w] = p;
    }
    __syncthreads();
    if (d == 0) sembn = sqrtf(red[0] + red[1] + red[2] + red[3]);
    __syncthreads();
    float embn = sembn;
    float thr = *thr_p;
    int row = blockIdx.x * 4 + w;
    const float* ar = A + (size_t)row * D;
    float num = 0.f, sq = 0.f;
#pragma unroll
    for (int s = 0; s < 4; s++) {
        float v = ar[lane + 64 * s];
        num += v * se[lane + 64 * s];
        sq += v * v;
    }
#pragma unroll
    for (int o = 32; o; o >>= 1) { num += __shfl_down(num, o); sq += __shfl_down(sq, o); }
    if (lane == 0) {
        float den = fmaxf(sqrtf(sq) * embn, 1e-8f);
        float e = num / den;
        endv[row] = e;
        float mv = e > thr ? 1.f : 0.f;
        m[row] = mv;
        if (mv != 0.f) atomicAdd(&scnt, 1.f);
    }
    __syncthreads();
    if (d == 0 && scnt != 0.f) atomicAdd(cnt, scnt);
}

// ---------------------------------------------------------------------------
// G = sum_i m_i a_i a_i^T (256x256), split-K with atomics. grid (16, 10).
constexpr int GCHUNK = 1000;
__global__ __launch_bounds__(256) void G_kernel(const float* __restrict__ A,
                                                const float* __restrict__ m,
                                                float* __restrict__ G) {
    __shared__ float SA[8][64], SB[8][64];
    int ti = blockIdx.x >> 2, tj = blockIdx.x & 3;
    int base = blockIdx.y * GCHUNK;
    int tid = threadIdx.x;
    int tx = tid & 15, ty = tid >> 4;
    float acc[4][4] = {};
    for (int g0 = 0; g0 < GCHUNK; g0 += 8) {
        for (int l = tid; l < 512; l += 256) {
            int rr = l >> 6, c = l & 63;
            int r = base + g0 + rr;
            float mv = m[r];
            SA[rr][c] = A[(size_t)r * D + ti * 64 + c] * mv;
            SB[rr][c] = A[(size_t)r * D + tj * 64 + c];
        }
        __syncthreads();
#pragma unroll
        for (int rr = 0; rr < 8; rr++) {
            float av[4], bv[4];
#pragma unroll
            for (int i = 0; i < 4; i++) av[i] = SA[rr][ty * 4 + i];
#pragma unroll
            for (int j = 0; j < 4; j++) bv[j] = SB[rr][tx * 4 + j];
#pragma unroll
            for (int i = 0; i < 4; i++)
#pragma unroll
                for (int j = 0; j < 4; j++) acc[i][j] += av[i] * bv[j];
        }
        __syncthreads();
    }
#pragma unroll
    for (int i = 0; i < 4; i++)
#pragma unroll
        for (int j = 0; j < 4; j++)
            atomicAdd(&G[(ti * 64 + ty * 4 + i) * D + tj * 64 + tx * 4 + j], acc[i][j]);
}

// ---------------------------------------------------------------------------
__global__ __launch_bounds__(256) void final_kernel(const int* __restrict__ cols,
                                                    const int* __restrict__ rowcnt,
                                                    const float* __restrict__ m,
                                                    const float* __restrict__ A,
                                                    const float* __restrict__ H,
                                                    double* __restrict__ total,
                                                    double* __restrict__ tr) {
    int i = blockIdx.x;
    if (m[i] == 0.f) return;
    __shared__ float sa[D];
    __shared__ int sc[CAP];
    __shared__ float red[4], red2[4];
    __shared__ float sdenom;
    int d = threadIdx.x;
    float av = A[(size_t)i * D + d];
    sa[d] = av;
    int cnt = rowcnt[i];
    if (d < cnt) sc[d] = cols[i * CAP + d];
    float p = wave_red64(av * H[(size_t)i * D + d]);
    int w = d >> 6, lane = d & 63;
    if (lane == 0) red[w] = p;
    __syncthreads();
    if (d == 0) sdenom = fmaxf(sqrtf(red[0] + red[1] + red[2] + red[3]), 1e-12f);
    __syncthreads();
    float accs = 0.f, acct = 0.f;
    for (int k = w; k < cnt; k += 4) {
        int j = sc[k];
        if (m[j] != 0.f) {
            const float* aj = A + (size_t)j * D;
            float t = sa[lane] * aj[lane] + sa[lane + 64] * aj[lane + 64]
                    + sa[lane + 128] * aj[lane + 128] + sa[lane + 192] * aj[lane + 192];
            t = wave_red64(t);
            if (lane == 0) { accs += t; if (j == i) acct += t; }
        }
    }
    if (lane == 0) { red[w] = accs; red2[w] = acct; }
    __syncthreads();
    if (d == 0) {
        float s = red[0] + red[1] + red[2] + red[3];
        float t2 = red2[0] + red2[1] + red2[2] + red2[3];
        double inv = 1.0 / (double)sdenom;
        if (s != 0.f) atomicAdd(total, (double)s * inv);
        if (t2 != 0.f) atomicAdd(tr, (double)t2 * inv);
    }
}

// ---------------------------------------------------------------------------
__global__ void scalars_kernel(const float* __restrict__ cnt,
                               const double* __restrict__ total,
                               const double* __restrict__ tr,
                               float* __restrict__ out) {
    float c = *cnt;
    float T = (float)*total;
    float R = (float)*tr;
    bool has = c > 0.f;
    out[0] = has ? (T / fmaxf(c, 1.f)) : 0.f;
    out[1] = has ? (2.f * T / (R * (R - 1.f) + 1e-4f)) : 0.f;
    out[2] = has ? R : 0.f;
}

// ---------------------------------------------------------------------------
extern "C" void kernel_launch(void* const* d_in, const int* in_sizes, int n_in,
                              void* d_out, int out_size, void* d_ws, size_t ws_size,
                              hipStream_t stream) {
    (void)in_sizes; (void)n_in; (void)out_size; (void)ws_size;
    const float* adj  = (const float*)d_in[0];
    const float* Fda  = (const float*)d_in[1];
    const float* Qadj = (const float*)d_in[2];
    const float* Fq   = (const float*)d_in[3];
    const int*   cand = (const int*)d_in[4];
    const float* thr  = (const float*)d_in[6];
    const float* W1da = (const float*)d_in[7];
    const float* W1q  = (const float*)d_in[8];
    const float* W2da = (const float*)d_in[9];
    const float* W2q  = (const float*)d_in[10];

    float* out = (float*)d_out;
    float* o_end    = out;
    float* o_attda2 = out + NDA;
    float* o_attq2  = out + NDA + (size_t)NDA * D;
    float* o_sc     = o_attq2 + NQ * D;

    char* w = (char*)d_ws;
    size_t off = 0;
    auto alloc = [&](size_t b) { size_t r = off; off += (b + 255) & ~(size_t)255; return r; };
    float* bufA = (float*)(w + alloc((size_t)NDA * D * 4));   // S1 (128-wide) -> T (256-wide)
    float* bufB = (float*)(w + alloc((size_t)NDA * D * 4));   // da1 -> H
    float* bufC = (float*)(w + alloc((size_t)NDA * D * 4));   // da2
    __hip_bfloat16* attda1_bf = (__hip_bfloat16*)(w + alloc((size_t)NDA * D * 2));
    int* colsb   = (int*)(w + alloc((size_t)NDA * CAP * 4));
    int* rowcntb = (int*)(w + alloc((size_t)NDA * 4));
    float* mbuf  = (float*)(w + alloc((size_t)NDA * 4));
    // Zero-initialized region: G | M | rsq_da1 | rsq_da2 | rnqsq1 | rnqsq2 | cnt,total,tr
    size_t zsz = 262144 * 2 + 40000 * 4 * 2 + 256 * 2 + 64;
    char* zbase = w + alloc(zsz);
    float* Gb      = (float*)zbase;                               // 256 KB
    float* Mb      = (float*)(zbase + 262144);                    // 256 KB
    float* rsq1    = (float*)(zbase + 524288);                    // 40 KB
    float* rsq2    = (float*)(zbase + 524288 + 160000);           // 40 KB
    float* rnqsq1  = (float*)(zbase + 524288 + 320000);           // 256 B
    float* rnqsq2  = (float*)(zbase + 524288 + 320256);           // 256 B
    float* cntb    = (float*)(zbase + 524288 + 320512);
    double* totb   = (double*)(zbase + 524288 + 320520);
    double* trb    = (double*)(zbase + 524288 + 320528);
    float* q1b  = (float*)(w + alloc((size_t)NQ * D * 4));
    float* aq1  = (float*)(w + alloc((size_t)NQ * D * 4));
    float* q2b  = (float*)(w + alloc((size_t)NQ * D * 4));
    float* embb = (float*)(w + alloc((size_t)D * 4));

    hipMemsetAsync(zbase, 0, zsz, stream);

    const dim3 gBig((NDA + 63) / 64, D / 64);

    build_csr<<<NDA, 256, 0, stream>>>(adj, colsb, rowcntb);
    // Layer 1 (reassociated: da1 = lrelu((adj@Fda)@W1))
    qpath_kernel<<<D / 64, 256, 0, stream>>>(Fq, W1q, Qadj, q1b, rnqsq1, DIN);
    spmm_f32<DIN><<<NDA, DIN, 0, stream>>>(colsb, rowcntb, Fda, bufA);               // S1
    gemm64<true, false, true><<<gBig, 256, 0, stream>>>(bufA, W1da, bufB, nullptr,
                                                        attda1_bf, rsq1, NDA, D, DIN); // da1 + att_da1(bf16) + rowsq
    candM_split<<<dim3(4, 4, CND / CCH), 256, 0, stream>>>(bufB, cand, rsq1, Mb);
    hq_attq_kernel<false><<<D / 64, 256, 0, stream>>>(q1b, rnqsq1, Mb, aq1, nullptr); // att_q1 (+zero M)
    // Layer 2 (reassociated: da2 = lrelu((adj@att_da1)@W2))
    qpath_kernel<<<D / 64, 256, 0, stream>>>(aq1, W2q, Qadj, q2b, rnqsq2, D);
    spmm_bf16<<<NDA, D, 0, stream>>>(colsb, rowcntb, attda1_bf, bufA);               // T
    gemm64<true, true, false><<<gBig, 256, 0, stream>>>(bufA, W2da, bufC, o_attda2,
                                                        nullptr, rsq2, NDA, D, D);   // da2 + att_da2 + rowsq
    candM_split<<<dim3(4, 4, CND / CCH), 256, 0, stream>>>(bufC, cand, rsq2, Mb);
    hq_attq_kernel<true><<<D / 64, 256, 0, stream>>>(q2b, rnqsq2, Mb, o_attq2, embb); // att_q2 + emb
    // Scoring
    end_kernel<<<NDA / 4, 256, 0, stream>>>(o_attda2, embb, thr, o_end, mbuf, cntb);
    G_kernel<<<dim3(16, NDA / GCHUNK), 256, 0, stream>>>(o_attda2, mbuf, Gb);
    gemm64<false, false, false><<<gBig, 256, 0, stream>>>(o_attda2, Gb, bufB, nullptr,
                                                          nullptr, nullptr, NDA, D, D); // H
    final_kernel<<<NDA, 256, 0, stream>>>(colsb, rowcntb, mbuf, o_attda2, bufB, totb, trb);
    scalars_kernel<<<1, 1, 0, stream>>>(cntb, totb, trb, o_sc);
}

// Round 5
// 1045.547 us; speedup vs baseline: 1.1077x; 1.1077x over previous
//
#include <hip/hip_runtime.h>
#include <hip/hip_bf16.h>

// Problem constants (fixed by setup_inputs)
constexpr int NDA = 10000;   // target graph nodes
constexpr int NQ  = 64;      // query graph nodes
constexpr int CND = 1024;    // candidate set size
constexpr int DIN = 128;     // input feature dim
constexpr int D   = 256;     // hidden dim
constexpr int CAP = 96;      // max nnz per adjacency row (Poisson(20); P(>96) ~ 0)

#define LRELU(x) ((x) >= 0.f ? (x) : 0.01f * (x))

typedef __attribute__((ext_vector_type(8))) short short8;   // 8 bf16 (4 VGPRs)
typedef __attribute__((ext_vector_type(4))) float f32x4;    // MFMA accumulator

__device__ __forceinline__ float wave_red64(float v) {
#pragma unroll
    for (int o = 32; o; o >>= 1) v += __shfl_down(v, o);
    return v;
}

// ---------------------------------------------------------------------------
// CSR build: one block per row, scan 10000 floats, record nonzero columns.
__global__ __launch_bounds__(256) void build_csr(const float* __restrict__ adj,
                                                 int* __restrict__ cols,
                                                 int* __restrict__ rowcnt) {
    int row = blockIdx.x;
    __shared__ int scnt;
    if (threadIdx.x == 0) scnt = 0;
    __syncthreads();
    const float4* rp = (const float4*)(adj + (size_t)row * NDA);
    for (int i = threadIdx.x; i < NDA / 4; i += 256) {
        float4 v = rp[i];
        if (v.x != 0.f) { int s = atomicAdd(&scnt, 1); if (s < CAP) cols[row * CAP + s] = 4 * i; }
        if (v.y != 0.f) { int s = atomicAdd(&scnt, 1); if (s < CAP) cols[row * CAP + s] = 4 * i + 1; }
        if (v.z != 0.f) { int s = atomicAdd(&scnt, 1); if (s < CAP) cols[row * CAP + s] = 4 * i + 2; }
        if (v.w != 0.f) { int s = atomicAdd(&scnt, 1); if (s < CAP) cols[row * CAP + s] = 4 * i + 3; }
    }
    __syncthreads();
    if (threadIdx.x == 0) rowcnt[row] = min(scnt, CAP);
}

// ---------------------------------------------------------------------------
// SpMM via CSR over fp32 input, width W, bf16 output.
template <int W>
__global__ void spmm_f32(const int* __restrict__ cols,
                         const int* __restrict__ rowcnt,
                         const float* __restrict__ X,
                         __hip_bfloat16* __restrict__ out) {
    int row = blockIdx.x;
    int d = threadIdx.x;
    int cnt = rowcnt[row];
    __shared__ int sc[CAP];
    if (d < CAP && d < cnt) sc[d] = cols[row * CAP + d];
    __syncthreads();
    float a0 = 0.f, a1 = 0.f, a2 = 0.f, a3 = 0.f;
    int k = 0;
    for (; k + 4 <= cnt; k += 4) {
        a0 += X[(size_t)sc[k + 0] * W + d];
        a1 += X[(size_t)sc[k + 1] * W + d];
        a2 += X[(size_t)sc[k + 2] * W + d];
        a3 += X[(size_t)sc[k + 3] * W + d];
    }
    for (; k < cnt; k++) a0 += X[(size_t)sc[k] * W + d];
    out[(size_t)row * W + d] = __float2bfloat16((a0 + a1) + (a2 + a3));
}

// SpMM over bf16 input (lrelu pre-applied by producer), width 256, bf16 out.
__global__ void spmm_bf16(const int* __restrict__ cols,
                          const int* __restrict__ rowcnt,
                          const __hip_bfloat16* __restrict__ X,
                          __hip_bfloat16* __restrict__ out) {
    int row = blockIdx.x;
    int d = threadIdx.x;
    int cnt = rowcnt[row];
    __shared__ int sc[CAP];
    if (d < CAP && d < cnt) sc[d] = cols[row * CAP + d];
    __syncthreads();
    float a0 = 0.f, a1 = 0.f, a2 = 0.f, a3 = 0.f;
    int k = 0;
    for (; k + 4 <= cnt; k += 4) {
        a0 += __bfloat162float(X[(size_t)sc[k + 0] * D + d]);
        a1 += __bfloat162float(X[(size_t)sc[k + 1] * D + d]);
        a2 += __bfloat162float(X[(size_t)sc[k + 2] * D + d]);
        a3 += __bfloat162float(X[(size_t)sc[k + 3] * D + d]);
    }
    for (; k < cnt; k++) a0 += __bfloat162float(X[(size_t)sc[k] * D + d]);
    out[(size_t)row * D + d] = __float2bfloat16((a0 + a1) + (a2 + a3));
}

// ---------------------------------------------------------------------------
// bf16 MFMA GEMM: C[M,256] = A[M,KDIM](bf16) @ B[KDIM,256](fp32, staged->bf16).
// Block 256 thr = 4 waves; tile 64(M) x 64(N); K-chunk 32 via 16x16x32 MFMA.
// Wave w owns rows [w*16,w*16+16); 4 n-subtiles of 16.
// EPI 0: C=acc. EPI 1 (L1): C=lrelu(acc); bfout=bf16(lrelu(C)); rowsq+=C^2.
// EPI 2 (L2): C=lrelu(acc); C2=lrelu(C) fp32; bfout=bf16(lrelu(C)); rowsq+=C^2.
// LDS stride 56 bf16 (112 B row): 16B-aligned frag reads, 2-way banks (free).
template <int KDIM, int EPI>
__global__ __launch_bounds__(256) void mfma_gemm(const __hip_bfloat16* __restrict__ A,
                                                 const float* __restrict__ B,
                                                 float* __restrict__ C,
                                                 float* __restrict__ C2,
                                                 __hip_bfloat16* __restrict__ bfout,
                                                 float* __restrict__ rowsq,
                                                 int M) {
    __shared__ __hip_bfloat16 Al[64][56];
    __shared__ __hip_bfloat16 Bl[64][56];
    const int bm = blockIdx.x * 64;
    const int bn = blockIdx.y * 64;
    const int tid = threadIdx.x;
    const int wave = tid >> 6, lane = tid & 63;
    const int quad = lane >> 4, l16 = lane & 15;
    f32x4 acc[4] = {};
    for (int k0 = 0; k0 < KDIM; k0 += 32) {
        {   // stage A: thread t -> row m=t>>2, 8 bf16 at koff=(t&3)*8
            int m = tid >> 2;
            int koff = (tid & 3) * 8;
            uint4 v = make_uint4(0, 0, 0, 0);
            if (bm + m < M) v = *(const uint4*)(A + (size_t)(bm + m) * KDIM + k0 + koff);
            *(uint4*)(&Al[m][koff]) = v;
        }
        {   // stage B (transposed to [n][k]): thread t -> n=t>>2, k=(t&3)*8..+8
            int nl = tid >> 2;
            int kb = (tid & 3) * 8;
            __hip_bfloat16 tmp[8];
#pragma unroll
            for (int u = 0; u < 8; u++)
                tmp[u] = __float2bfloat16(B[(size_t)(k0 + kb + u) * D + bn + nl]);
            *(uint4*)(&Bl[nl][kb]) = *(const uint4*)tmp;
        }
        __syncthreads();
        short8 af = *(const short8*)(&Al[wave * 16 + l16][quad * 8]);
#pragma unroll
        for (int ns = 0; ns < 4; ns++) {
            short8 bf = *(const short8*)(&Bl[ns * 16 + l16][quad * 8]);
            acc[ns] = __builtin_amdgcn_mfma_f32_16x16x32_bf16(af, bf, acc[ns], 0, 0, 0);
        }
        __syncthreads();
    }
    // epilogue: D layout col=l16, row=quad*4+reg
    float rp[4] = {};
#pragma unroll
    for (int ns = 0; ns < 4; ns++) {
        int col = bn + ns * 16 + l16;
#pragma unroll
        for (int reg = 0; reg < 4; reg++) {
            int r = bm + wave * 16 + quad * 4 + reg;
            if (r < M) {
                float v = acc[ns][reg];
                if (EPI == 0) {
                    C[(size_t)r * D + col] = v;
                } else {
                    float da = LRELU(v);
                    C[(size_t)r * D + col] = da;
                    rp[reg] += da * da;
                    float att = LRELU(da);
                    if (EPI == 2) C2[(size_t)r * D + col] = att;
                    bfout[(size_t)r * D + col] = __float2bfloat16(att);
                }
            }
        }
    }
    if (EPI != 0) {
#pragma unroll
        for (int reg = 0; reg < 4; reg++) {
            int r = bm + wave * 16 + quad * 4 + reg;
            if (r < M && rp[reg] != 0.f) atomicAdd(&rowsq[r], rp[reg]);
        }
    }
}

// ---------------------------------------------------------------------------
// A^T-A-shaped MFMA: Out[256,256] += sum_r sA_r * A[r,ti-slice]^T A[r,tj-slice].
// GATHER: rows cand[g], sA = 1/max(sqrt(rowsq[cand[g]]),eps) (cosine P^n).
// !GATHER: rows g (guarded < NDA), sA = m[g] (mask).  Atomic accumulate.
// grid (4,4,NZ); each block handles nrc rows in 32-row k-chunks.
template <bool GATHER>
__global__ __launch_bounds__(256) void ata_mfma(const float* __restrict__ A,
                                                const int* __restrict__ cand,
                                                const float* __restrict__ scale,
                                                float* __restrict__ Out,
                                                int nrc) {
    __shared__ __hip_bfloat16 SAl[64][56];
    __shared__ __hip_bfloat16 SBl[64][56];
    __shared__ int sidx[512];
    __shared__ float sscl[512];
    const int ti = blockIdx.x, tj = blockIdx.y;
    const int base = blockIdx.z * nrc;
    const int tid = threadIdx.x;
    const int wave = tid >> 6, lane = tid & 63;
    const int quad = lane >> 4, l16 = lane & 15;
    for (int i = tid; i < nrc; i += 256) {
        int g = base + i;
        if (GATHER) {
            int ri = cand[g];
            sidx[i] = ri;
            sscl[i] = 1.f / fmaxf(sqrtf(scale[ri]), 1e-12f);
        } else {
            if (g < NDA) { sidx[i] = g; sscl[i] = scale[g]; }
            else         { sidx[i] = -1; sscl[i] = 0.f; }
        }
    }
    __syncthreads();
    f32x4 acc[4] = {};
    for (int kc = 0; kc < nrc; kc += 32) {
        {   // stage both tiles transposed: thread t -> c=t>>2, k=(t&3)*8..+8
            int c = tid >> 2;
            int kb = (tid & 3) * 8;
            __hip_bfloat16 ta[8], tb[8];
#pragma unroll
            for (int u = 0; u < 8; u++) {
                int ri = sidx[kc + kb + u];
                float av = 0.f, bv = 0.f;
                if (ri >= 0) {
                    av = A[(size_t)ri * D + ti * 64 + c] * sscl[kc + kb + u];
                    bv = A[(size_t)ri * D + tj * 64 + c];
                }
                ta[u] = __float2bfloat16(av);
                tb[u] = __float2bfloat16(bv);
            }
            *(uint4*)(&SAl[c][kb]) = *(const uint4*)ta;
            *(uint4*)(&SBl[c][kb]) = *(const uint4*)tb;
        }
        __syncthreads();
        short8 af = *(const short8*)(&SAl[wave * 16 + l16][quad * 8]);
#pragma unroll
        for (int ns = 0; ns < 4; ns++) {
            short8 bf = *(const short8*)(&SBl[ns * 16 + l16][quad * 8]);
            acc[ns] = __builtin_amdgcn_mfma_f32_16x16x32_bf16(af, bf, acc[ns], 0, 0, 0);
        }
        __syncthreads();
    }
#pragma unroll
    for (int ns = 0; ns < 4; ns++) {
        int col = tj * 64 + ns * 16 + l16;
#pragma unroll
        for (int reg = 0; reg < 4; reg++) {
            int row = ti * 64 + wave * 16 + quad * 4 + reg;
            float v = acc[ns][reg];
            if (v != 0.f) atomicAdd(&Out[(size_t)row * D + col], v);
        }
    }
}

// ---------------------------------------------------------------------------
// Fused query path: Xq = Fq @ Wq, q_out = lrelu(Qadj @ Xq), accumulate per-row
// sum-of-squares of q_out into rnqsq[64] (global atomics; pre-zeroed buffer).
__global__ __launch_bounds__(256) void qpath_kernel(const float* __restrict__ Fq,
                                                    const float* __restrict__ Wq,
                                                    const float* __restrict__ Qadj,
                                                    float* __restrict__ q_out,
                                                    float* __restrict__ rnqsq,
                                                    int K) {
    __shared__ float As[16][68];
    __shared__ float Bs[16][68];
    __shared__ float Xs[64][68];
    __shared__ float Qs[64][68];
    __shared__ float sq[64];
    const int bn = blockIdx.x * 64;
    const int tid = threadIdx.x;
    const int tx = tid & 15, ty = tid >> 4;
    float acc[4][4] = {};
    for (int k0 = 0; k0 < K; k0 += 16) {
        {
            int m = tid >> 2;
            int k4 = (tid & 3) * 4;
            float4 v = *(const float4*)(Fq + (size_t)m * K + k0 + k4);
            As[k4 + 0][m] = v.x; As[k4 + 1][m] = v.y; As[k4 + 2][m] = v.z; As[k4 + 3][m] = v.w;
        }
        {
            int kk = tid >> 4;
            int n4 = (tid & 15) * 4;
            float4 v = *(const float4*)(Wq + (size_t)(k0 + kk) * D + bn + n4);
            Bs[kk][n4 + 0] = v.x; Bs[kk][n4 + 1] = v.y; Bs[kk][n4 + 2] = v.z; Bs[kk][n4 + 3] = v.w;
        }
        __syncthreads();
#pragma unroll
        for (int kk = 0; kk < 16; kk++) {
            float av[4], bv[4];
#pragma unroll
            for (int i = 0; i < 4; i++) av[i] = As[kk][ty * 4 + i];
#pragma unroll
            for (int j = 0; j < 4; j++) bv[j] = Bs[kk][tx * 4 + j];
#pragma unroll
            for (int i = 0; i < 4; i++)
#pragma unroll
                for (int j = 0; j < 4; j++) acc[i][j] += av[i] * bv[j];
        }
        __syncthreads();
    }
#pragma unroll
    for (int i = 0; i < 4; i++)
#pragma unroll
        for (int j = 0; j < 4; j++) Xs[ty * 4 + i][tx * 4 + j] = acc[i][j];
    for (int l = tid; l < NQ * NQ; l += 256) Qs[l >> 6][l & 63] = Qadj[l];
    if (tid < 64) sq[tid] = 0.f;
    __syncthreads();
    float a2[4][4] = {};
#pragma unroll 4
    for (int kk = 0; kk < NQ; kk++) {
        float av[4], bv[4];
#pragma unroll
        for (int i = 0; i < 4; i++) av[i] = Qs[ty * 4 + i][kk];
#pragma unroll
        for (int j = 0; j < 4; j++) bv[j] = Xs[kk][tx * 4 + j];
#pragma unroll
        for (int i = 0; i < 4; i++)
#pragma unroll
            for (int j = 0; j < 4; j++) a2[i][j] += av[i] * bv[j];
    }
#pragma unroll
    for (int i = 0; i < 4; i++) {
        float rp = 0.f;
#pragma unroll
        for (int j = 0; j < 4; j++) {
            float v = LRELU(a2[i][j]);
            q_out[(ty * 4 + i) * D + bn + tx * 4 + j] = v;
            rp += v * v;
        }
        atomicAdd(&sq[ty * 4 + i], rp);
    }
    __syncthreads();
    if (tid < 64) atomicAdd(&rnqsq[tid], sq[tid]);
}

// ---------------------------------------------------------------------------
// Fused h + att_q + emb: h = (diag(1/|q_r|) q) @ M; block owns a 64-col slice.
// Consume-zeros M for the next layer.
template <bool EMB>
__global__ __launch_bounds__(256) void hq_attq_kernel(const float* __restrict__ q,
                                                      const float* __restrict__ rnqsq,
                                                      float* __restrict__ M,
                                                      float* __restrict__ attq,
                                                      float* __restrict__ emb) {
    __shared__ float As[16][68];
    __shared__ float Bs[16][68];
    __shared__ float cred[16][64];
    __shared__ float sinv[64];
    const int bn = blockIdx.x * 64;
    const int tid = threadIdx.x;
    const int tx = tid & 15, ty = tid >> 4;
    const int am = tid >> 2;
    const float ascale = 1.f / fmaxf(sqrtf(rnqsq[am]), 1e-12f);
    float acc[4][4] = {};
    const float4 z4 = make_float4(0.f, 0.f, 0.f, 0.f);
    for (int k0 = 0; k0 < D; k0 += 16) {
        {
            int k4 = (tid & 3) * 4;
            float4 v = *(const float4*)(q + (size_t)am * D + k0 + k4);
            As[k4 + 0][am] = v.x * ascale; As[k4 + 1][am] = v.y * ascale;
            As[k4 + 2][am] = v.z * ascale; As[k4 + 3][am] = v.w * ascale;
        }
        {
            int kk = tid >> 4;
            int n4 = (tid & 15) * 4;
            float4 v = *(const float4*)(M + (size_t)(k0 + kk) * D + bn + n4);
            *(float4*)(M + (size_t)(k0 + kk) * D + bn + n4) = z4;   // consume-and-zero
            Bs[kk][n4 + 0] = v.x; Bs[kk][n4 + 1] = v.y; Bs[kk][n4 + 2] = v.z; Bs[kk][n4 + 3] = v.w;
        }
        __syncthreads();
#pragma unroll
        for (int kk = 0; kk < 16; kk++) {
            float av[4], bv[4];
#pragma unroll
            for (int i = 0; i < 4; i++) av[i] = As[kk][ty * 4 + i];
#pragma unroll
            for (int j = 0; j < 4; j++) bv[j] = Bs[kk][tx * 4 + j];
#pragma unroll
            for (int i = 0; i < 4; i++)
#pragma unroll
                for (int j = 0; j < 4; j++) acc[i][j] += av[i] * bv[j];
        }
        __syncthreads();
    }
#pragma unroll
    for (int j = 0; j < 4; j++) {
        float p = 0.f;
#pragma unroll
        for (int i = 0; i < 4; i++) p += acc[i][j] * acc[i][j];
        cred[ty][tx * 4 + j] = p;
    }
    __syncthreads();
    if (tid < 64) {
        float s = 0.f;
#pragma unroll
        for (int t = 0; t < 16; t++) s += cred[t][tid];
        sinv[tid] = 1.f / fmaxf(sqrtf(s), 1e-12f);
    }
    __syncthreads();
    float esum[4] = {};
#pragma unroll
    for (int i = 0; i < 4; i++) {
        int r = ty * 4 + i;
        float4 q4 = *(const float4*)(q + (size_t)r * D + bn + tx * 4);
        float4 v;
        v.x = LRELU(q4.x + acc[i][0] * sinv[tx * 4 + 0]);
        v.y = LRELU(q4.y + acc[i][1] * sinv[tx * 4 + 1]);
        v.z = LRELU(q4.z + acc[i][2] * sinv[tx * 4 + 2]);
        v.w = LRELU(q4.w + acc[i][3] * sinv[tx * 4 + 3]);
        *(float4*)(attq + (size_t)r * D + bn + tx * 4) = v;
        if (EMB) { esum[0] += v.x; esum[1] += v.y; esum[2] += v.z; esum[3] += v.w; }
    }
    if (EMB) {
        __syncthreads();
#pragma unroll
        for (int j = 0; j < 4; j++) cred[ty][tx * 4 + j] = esum[j];
        __syncthreads();
        if (tid < 64) {
            float s = 0.f;
#pragma unroll
            for (int t = 0; t < 16; t++) s += cred[t][tid];
            emb[bn + tid] = s * (1.f / (float)NQ);
        }
    }
}

// ---------------------------------------------------------------------------
// end[i] = (a_i . emb)/max(|a_i|*|emb|,1e-8); m[i] = end>thr; cnt += m.
__global__ __launch_bounds__(256) void end_kernel(const float* __restrict__ A,
                                                  const float* __restrict__ emb,
                                                  const float* __restrict__ thr_p,
                                                  float* __restrict__ endv,
                                                  float* __restrict__ m,
                                                  float* __restrict__ cnt) {
    __shared__ float se[D];
    __shared__ float red[4];
    __shared__ float scnt, sembn;
    int d = threadIdx.x;
    se[d] = emb[d];
    if (d == 0) scnt = 0.f;
    __syncthreads();
    int w = d >> 6, lane = d & 63;
    {
        float p = wave_red64(se[d] * se[d]);
        if (lane == 0) red[w] = p;
    }
    __syncthreads();
    if (d == 0) sembn = sqrtf(red[0] + red[1] + red[2] + red[3]);
    __syncthreads();
    float embn = sembn;
    float thr = *thr_p;
    int row = blockIdx.x * 4 + w;
    const float* ar = A + (size_t)row * D;
    float num = 0.f, sq = 0.f;
#pragma unroll
    for (int s = 0; s < 4; s++) {
        float v = ar[lane + 64 * s];
        num += v * se[lane + 64 * s];
        sq += v * v;
    }
#pragma unroll
    for (int o = 32; o; o >>= 1) { num += __shfl_down(num, o); sq += __shfl_down(sq, o); }
    if (lane == 0) {
        float den = fmaxf(sqrtf(sq) * embn, 1e-8f);
        float e = num / den;
        endv[row] = e;
        float mv = e > thr ? 1.f : 0.f;
        m[row] = mv;
        if (mv != 0.f) atomicAdd(&scnt, 1.f);
    }
    __syncthreads();
    if (d == 0 && scnt != 0.f) atomicAdd(cnt, scnt);
}

// ---------------------------------------------------------------------------
__global__ __launch_bounds__(256) void final_kernel(const int* __restrict__ cols,
                                                    const int* __restrict__ rowcnt,
                                                    const float* __restrict__ m,
                                                    const float* __restrict__ A,
                                                    const float* __restrict__ H,
                                                    double* __restrict__ total,
                                                    double* __restrict__ tr) {
    int i = blockIdx.x;
    if (m[i] == 0.f) return;
    __shared__ float sa[D];
    __shared__ int sc[CAP];
    __shared__ float red[4], red2[4];
    __shared__ float sdenom;
    int d = threadIdx.x;
    float av = A[(size_t)i * D + d];
    sa[d] = av;
    int cnt = rowcnt[i];
    if (d < cnt) sc[d] = cols[i * CAP + d];
    float p = wave_red64(av * H[(size_t)i * D + d]);
    int w = d >> 6, lane = d & 63;
    if (lane == 0) red[w] = p;
    __syncthreads();
    if (d == 0) sdenom = fmaxf(sqrtf(red[0] + red[1] + red[2] + red[3]), 1e-12f);
    __syncthreads();
    float accs = 0.f, acct = 0.f;
    for (int k = w; k < cnt; k += 4) {
        int j = sc[k];
        if (m[j] != 0.f) {
            const float* aj = A + (size_t)j * D;
            float t = sa[lane] * aj[lane] + sa[lane + 64] * aj[lane + 64]
                    + sa[lane + 128] * aj[lane + 128] + sa[lane + 192] * aj[lane + 192];
            t = wave_red64(t);
            if (lane == 0) { accs += t; if (j == i) acct += t; }
        }
    }
    if (lane == 0) { red[w] = accs; red2[w] = acct; }
    __syncthreads();
    if (d == 0) {
        float s = red[0] + red[1] + red[2] + red[3];
        float t2 = red2[0] + red2[1] + red2[2] + red2[3];
        double inv = 1.0 / (double)sdenom;
        if (s != 0.f) atomicAdd(total, (double)s * inv);
        if (t2 != 0.f) atomicAdd(tr, (double)t2 * inv);
    }
}

// ---------------------------------------------------------------------------
__global__ void scalars_kernel(const float* __restrict__ cnt,
                               const double* __restrict__ total,
                               const double* __restrict__ tr,
                               float* __restrict__ out) {
    float c = *cnt;
    float T = (float)*total;
    float R = (float)*tr;
    bool has = c > 0.f;
    out[0] = has ? (T / fmaxf(c, 1.f)) : 0.f;
    out[1] = has ? (2.f * T / (R * (R - 1.f) + 1e-4f)) : 0.f;
    out[2] = has ? R : 0.f;
}

// ---------------------------------------------------------------------------
extern "C" void kernel_launch(void* const* d_in, const int* in_sizes, int n_in,
                              void* d_out, int out_size, void* d_ws, size_t ws_size,
                              hipStream_t stream) {
    (void)in_sizes; (void)n_in; (void)out_size; (void)ws_size;
    const float* adj  = (const float*)d_in[0];
    const float* Fda  = (const float*)d_in[1];
    const float* Qadj = (const float*)d_in[2];
    const float* Fq   = (const float*)d_in[3];
    const int*   cand = (const int*)d_in[4];
    const float* thr  = (const float*)d_in[6];
    const float* W1da = (const float*)d_in[7];
    const float* W1q  = (const float*)d_in[8];
    const float* W2da = (const float*)d_in[9];
    const float* W2q  = (const float*)d_in[10];

    float* out = (float*)d_out;
    float* o_end    = out;
    float* o_attda2 = out + NDA;
    float* o_attq2  = out + NDA + (size_t)NDA * D;
    float* o_sc     = o_attq2 + NQ * D;

    char* w = (char*)d_ws;
    size_t off = 0;
    auto alloc = [&](size_t b) { size_t r = off; off += (b + 255) & ~(size_t)255; return r; };
    float* bufB = (float*)(w + alloc((size_t)NDA * D * 4));   // da1 -> H
    float* bufC = (float*)(w + alloc((size_t)NDA * D * 4));   // da2
    __hip_bfloat16* S1bf      = (__hip_bfloat16*)(w + alloc((size_t)NDA * DIN * 2));
    __hip_bfloat16* Tbf       = (__hip_bfloat16*)(w + alloc((size_t)NDA * D * 2));
    __hip_bfloat16* attda1_bf = (__hip_bfloat16*)(w + alloc((size_t)NDA * D * 2));
    __hip_bfloat16* attda2_bf = (__hip_bfloat16*)(w + alloc((size_t)NDA * D * 2));
    int* colsb   = (int*)(w + alloc((size_t)NDA * CAP * 4));
    int* rowcntb = (int*)(w + alloc((size_t)NDA * 4));
    float* mbuf  = (float*)(w + alloc((size_t)NDA * 4));
    // Zero-initialized region: G | M | rsq1 | rsq2 | rnqsq1 | rnqsq2 | cnt,total,tr
    size_t zsz = 262144 * 2 + 160000 * 2 + 256 * 2 + 64;
    char* zbase = w + alloc(zsz);
    float* Gb      = (float*)zbase;
    float* Mb      = (float*)(zbase + 262144);
    float* rsq1    = (float*)(zbase + 524288);
    float* rsq2    = (float*)(zbase + 524288 + 160000);
    float* rnqsq1  = (float*)(zbase + 524288 + 320000);
    float* rnqsq2  = (float*)(zbase + 524288 + 320256);
    float* cntb    = (float*)(zbase + 524288 + 320512);
    double* totb   = (double*)(zbase + 524288 + 320520);
    double* trb    = (double*)(zbase + 524288 + 320528);
    float* q1b  = (float*)(w + alloc((size_t)NQ * D * 4));
    float* aq1  = (float*)(w + alloc((size_t)NQ * D * 4));
    float* q2b  = (float*)(w + alloc((size_t)NQ * D * 4));
    float* embb = (float*)(w + alloc((size_t)D * 4));

    hipMemsetAsync(zbase, 0, zsz, stream);

    const dim3 gMM((NDA + 63) / 64, D / 64);   // (157, 4)

    build_csr<<<NDA, 256, 0, stream>>>(adj, colsb, rowcntb);
    // Layer 1 (reassociated: da1 = lrelu((adj@Fda)@W1))
    qpath_kernel<<<D / 64, 256, 0, stream>>>(Fq, W1q, Qadj, q1b, rnqsq1, DIN);
    spmm_f32<DIN><<<NDA, DIN, 0, stream>>>(colsb, rowcntb, Fda, S1bf);
    mfma_gemm<DIN, 1><<<gMM, 256, 0, stream>>>(S1bf, W1da, bufB, nullptr,
                                               attda1_bf, rsq1, NDA);        // da1 + att_da1(bf16) + rsq1
    ata_mfma<true><<<dim3(4, 4, 4), 256, 0, stream>>>(bufB, cand, rsq1, Mb, 256);   // M (cosine x P)
    hq_attq_kernel<false><<<D / 64, 256, 0, stream>>>(q1b, rnqsq1, Mb, aq1, nullptr);
    // Layer 2 (reassociated: da2 = lrelu((adj@att_da1)@W2))
    qpath_kernel<<<D / 64, 256, 0, stream>>>(aq1, W2q, Qadj, q2b, rnqsq2, D);
    spmm_bf16<<<NDA, D, 0, stream>>>(colsb, rowcntb, attda1_bf, Tbf);
    mfma_gemm<D, 2><<<gMM, 256, 0, stream>>>(Tbf, W2da, bufC, o_attda2,
                                             attda2_bf, rsq2, NDA);          // da2 + att_da2 (f32+bf16) + rsq2
    ata_mfma<true><<<dim3(4, 4, 4), 256, 0, stream>>>(bufC, cand, rsq2, Mb, 256);
    hq_attq_kernel<true><<<D / 64, 256, 0, stream>>>(q2b, rnqsq2, Mb, o_attq2, embb);
    // Scoring
    end_kernel<<<NDA / 4, 256, 0, stream>>>(o_attda2, embb, thr, o_end, mbuf, cntb);
    ata_mfma<false><<<dim3(4, 4, 20), 256, 0, stream>>>(o_attda2, nullptr, mbuf, Gb, 512); // G
    mfma_gemm<D, 0><<<gMM, 256, 0, stream>>>(attda2_bf, Gb, bufB, nullptr,
                                             nullptr, nullptr, NDA);         // H = att_da2 @ G
    final_kernel<<<NDA, 256, 0, stream>>>(colsb, rowcntb, mbuf, o_attda2, bufB, totb, trb);
    scalars_kernel<<<1, 1, 0, stream>>>(cntb, totb, trb, o_sc);
}